// Round 1
// baseline (1675.722 us; speedup 1.0000x reference)
//
#include <hip/hip_runtime.h>

// ---------- constants (problem is fixed-shape) ----------
#define LTOK 36864     // H*W = 192*192
#define DIMC 384
#define NHEADS 6
#define HDIM 64
#define HIDD 768
#define NWIN 12        // windows per side
#define WSZ 16
#define OWS 24
#define KVTOK 576      // 24*24
#define QTOK 256       // 16*16
#define TBL 1521       // 39*39

using bf16x8 = __attribute__((ext_vector_type(8))) short;
using f32x4  = __attribute__((ext_vector_type(4))) float;

__device__ inline float bl(unsigned u) { return __uint_as_float(u << 16); }
__device__ inline float bh(unsigned u) { return __uint_as_float(u & 0xFFFF0000u); }
__device__ inline unsigned short f2bf(float f) {
  unsigned u = __float_as_uint(f);
  return (unsigned short)((u + 0x7FFFu + ((u >> 16) & 1u)) >> 16);
}

// ---------- weight convert+transpose: wt[n*K+k] = bf16(w[k*N+n]) ----------
__global__ void convt_kernel(const float* __restrict__ w, unsigned short* __restrict__ wt,
                             int K, int N) {
  int id = blockIdx.x * 256 + threadIdx.x;
  if (id >= K * N) return;
  int n = id / K;
  int k = id - n * K;
  wt[id] = f2bf(w[(size_t)k * N + n]);
}

// ---------- LayerNorm: fp32 in -> bf16 out, one wave per row (384 cols) ----------
__global__ __launch_bounds__(256) void ln_kernel(const float* __restrict__ x,
                                                 const float* __restrict__ g,
                                                 const float* __restrict__ b,
                                                 unsigned short* __restrict__ out) {
  int row = blockIdx.x * 4 + (threadIdx.x >> 6);
  int lane = threadIdx.x & 63;
  const float* xr = x + (size_t)row * DIMC;
  float v[6];
  float s = 0.f, ss = 0.f;
#pragma unroll
  for (int i = 0; i < 6; ++i) {
    v[i] = xr[lane + i * 64];
    s += v[i];
    ss += v[i] * v[i];
  }
#pragma unroll
  for (int off = 32; off; off >>= 1) {
    s += __shfl_xor(s, off);
    ss += __shfl_xor(ss, off);
  }
  float mean = s * (1.f / DIMC);
  float var = ss * (1.f / DIMC) - mean * mean;
  float rstd = rsqrtf(var + 1e-5f);
  unsigned short* outr = out + (size_t)row * DIMC;
#pragma unroll
  for (int i = 0; i < 6; ++i) {
    int c = lane + i * 64;
    outr[c] = f2bf((v[i] - mean) * rstd * g[c] + b[c]);
  }
}

// ---------- bf16 MFMA GEMM: C[M,N] = A[M,K] * Bt[N,K]^T + bias (+epilogue) ----------
// EPI 0: out bf16 = acc+bias
// EPI 1: out f32  = resid + acc + bias
// EPI 2: out bf16 = gelu_exact(acc+bias)
template <int EPI>
__global__ __launch_bounds__(256) void gemm_bf16(const unsigned short* __restrict__ A,
                                                 const unsigned short* __restrict__ Bt,
                                                 const float* __restrict__ bias,
                                                 const float* __restrict__ resid,
                                                 void* __restrict__ outv,
                                                 int M, int N, int K) {
  __shared__ unsigned short As[128][40];  // pad to 40 (80B rows, 16B-aligned)
  __shared__ unsigned short Bs[128][40];
  const int tid = threadIdx.x;
  const int m0 = blockIdx.y * 128;
  const int n0 = blockIdx.x * 128;
  const int lane = tid & 63;
  const int wave = tid >> 6;
  const int wr = wave >> 1;  // 0..1
  const int wc = wave & 1;   // 0..1

  f32x4 acc[4][4];
#pragma unroll
  for (int i = 0; i < 4; ++i)
#pragma unroll
    for (int j = 0; j < 4; ++j) acc[i][j] = (f32x4){0.f, 0.f, 0.f, 0.f};

  const int lrow = tid >> 2;        // 0..63
  const int lcol = (tid & 3) * 8;   // 0,8,16,24

  for (int k0 = 0; k0 < K; k0 += 32) {
    __syncthreads();
    *(uint4*)&As[lrow][lcol]      = *(const uint4*)&A[(size_t)(m0 + lrow) * K + k0 + lcol];
    *(uint4*)&As[lrow + 64][lcol] = *(const uint4*)&A[(size_t)(m0 + lrow + 64) * K + k0 + lcol];
    *(uint4*)&Bs[lrow][lcol]      = *(const uint4*)&Bt[(size_t)(n0 + lrow) * K + k0 + lcol];
    *(uint4*)&Bs[lrow + 64][lcol] = *(const uint4*)&Bt[(size_t)(n0 + lrow + 64) * K + k0 + lcol];
    __syncthreads();

    const int kid = (lane >> 4) * 8;
    bf16x8 af[4], bfr[4];
#pragma unroll
    for (int i = 0; i < 4; ++i)
      af[i] = *(const bf16x8*)&As[wr * 64 + i * 16 + (lane & 15)][kid];
#pragma unroll
    for (int j = 0; j < 4; ++j)
      bfr[j] = *(const bf16x8*)&Bs[wc * 64 + j * 16 + (lane & 15)][kid];
#pragma unroll
    for (int i = 0; i < 4; ++i)
#pragma unroll
      for (int j = 0; j < 4; ++j)
        acc[i][j] = __builtin_amdgcn_mfma_f32_16x16x32_bf16(af[i], bfr[j], acc[i][j], 0, 0, 0);
  }

  // epilogue: D row=(lane>>4)*4+r, col=lane&15 within each 16x16 tile
#pragma unroll
  for (int j = 0; j < 4; ++j) {
    int gcol = n0 + wc * 64 + j * 16 + (lane & 15);
    float bv = bias[gcol];
#pragma unroll
    for (int i = 0; i < 4; ++i) {
#pragma unroll
      for (int r = 0; r < 4; ++r) {
        int grow = m0 + wr * 64 + i * 16 + (lane >> 4) * 4 + r;
        float v = acc[i][j][r] + bv;
        size_t idx = (size_t)grow * N + gcol;
        if (EPI == 0) {
          ((unsigned short*)outv)[idx] = f2bf(v);
        } else if (EPI == 1) {
          ((float*)outv)[idx] = resid[idx] + v;
        } else {  // exact GELU
          float gv = 0.5f * v * (1.f + erff(v * 0.70710678118654752f));
          ((unsigned short*)outv)[idx] = f2bf(gv);
        }
      }
    }
  }
}

// ---------- attention: one block per (head, window); thread = one q token ----------
__global__ __launch_bounds__(256) void attn_kernel(const unsigned short* __restrict__ qkv,
                                                   const float* __restrict__ rpb,
                                                   unsigned short* __restrict__ att) {
  __shared__ unsigned short ks[KVTOK][HDIM];  // 73728 B
  __shared__ unsigned short vs[KVTOK][HDIM];  // 73728 B
  __shared__ float bs[TBL];                   // 6084 B
  const int head = blockIdx.x;  // 0..5
  const int win = blockIdx.y;   // 0..143
  const int wy = win / NWIN, wx = win - (win / NWIN) * NWIN;
  const int tid = threadIdx.x;

  for (int i = tid; i < TBL; i += 256) bs[i] = rpb[i * NHEADS + head];

  // stage K and V windows (24x24, padded-gather), bf16, 8 elems per vec load
#pragma unroll 2
  for (int i = 0; i < 18; ++i) {
    int vid = tid + i * 256;      // 0..4607
    int kt = vid >> 3;            // token 0..575
    int d8 = (vid & 7) * 8;
    int oy = kt / OWS, ox = kt - oy * OWS;
    int gy = wy * WSZ + oy - 4, gx = wx * WSZ + ox - 4;
    uint4 kv = {0, 0, 0, 0}, vv = {0, 0, 0, 0};
    if (gy >= 0 && gy < 192 && gx >= 0 && gx < 192) {
      size_t base = (size_t)(gy * 192 + gx) * 1152 + head * HDIM + d8;
      kv = *(const uint4*)(qkv + base + DIMC);
      vv = *(const uint4*)(qkv + base + 2 * DIMC);
    }
    *(uint4*)&ks[kt][d8] = kv;
    *(uint4*)&vs[kt][d8] = vv;
  }
  __syncthreads();

  // per-thread q row
  const int ty = tid >> 4, tx = tid & 15;
  const int qy = wy * WSZ + ty, qx = wx * WSZ + tx;
  float q[64];
  {
    const unsigned short* qp = qkv + (size_t)(qy * 192 + qx) * 1152 + head * HDIM;
#pragma unroll
    for (int c = 0; c < 8; ++c) {
      uint4 u = *(const uint4*)(qp + c * 8);
      q[c * 8 + 0] = bl(u.x) * 0.125f; q[c * 8 + 1] = bh(u.x) * 0.125f;
      q[c * 8 + 2] = bl(u.y) * 0.125f; q[c * 8 + 3] = bh(u.y) * 0.125f;
      q[c * 8 + 4] = bl(u.z) * 0.125f; q[c * 8 + 5] = bh(u.z) * 0.125f;
      q[c * 8 + 6] = bl(u.w) * 0.125f; q[c * 8 + 7] = bh(u.w) * 0.125f;
    }
  }

  float m = -1e30f, l = 0.f;
  float o[64];
#pragma unroll
  for (int d = 0; d < 64; ++d) o[d] = 0.f;

  for (int kt = 0; kt < KVTOK; ++kt) {
    float s0 = 0.f, s1 = 0.f, s2 = 0.f, s3 = 0.f;
#pragma unroll
    for (int c = 0; c < 8; ++c) {
      uint4 u = *(const uint4*)&ks[kt][c * 8];  // broadcast read
      s0 = fmaf(q[c * 8 + 0], bl(u.x), s0);
      s1 = fmaf(q[c * 8 + 1], bh(u.x), s1);
      s2 = fmaf(q[c * 8 + 2], bl(u.y), s2);
      s3 = fmaf(q[c * 8 + 3], bh(u.y), s3);
      s0 = fmaf(q[c * 8 + 4], bl(u.z), s0);
      s1 = fmaf(q[c * 8 + 5], bh(u.z), s1);
      s2 = fmaf(q[c * 8 + 6], bl(u.w), s2);
      s3 = fmaf(q[c * 8 + 7], bh(u.w), s3);
    }
    int oy = kt / OWS, ox = kt - (kt / OWS) * OWS;
    float s = (s0 + s1) + (s2 + s3) + bs[(ty - oy + 23) * 39 + (tx - ox + 23)];
    if (s > m) {  // guarded online-softmax rescale (rare: logits are tiny)
      float c = __expf(m - s);
      l *= c;
#pragma unroll
      for (int d = 0; d < 64; ++d) o[d] *= c;
      m = s;
    }
    float p = __expf(s - m);
    l += p;
#pragma unroll
    for (int c = 0; c < 8; ++c) {
      uint4 u = *(const uint4*)&vs[kt][c * 8];  // broadcast read
      o[c * 8 + 0] = fmaf(p, bl(u.x), o[c * 8 + 0]);
      o[c * 8 + 1] = fmaf(p, bh(u.x), o[c * 8 + 1]);
      o[c * 8 + 2] = fmaf(p, bl(u.y), o[c * 8 + 2]);
      o[c * 8 + 3] = fmaf(p, bh(u.y), o[c * 8 + 3]);
      o[c * 8 + 4] = fmaf(p, bl(u.z), o[c * 8 + 4]);
      o[c * 8 + 5] = fmaf(p, bh(u.z), o[c * 8 + 5]);
      o[c * 8 + 6] = fmaf(p, bl(u.w), o[c * 8 + 6]);
      o[c * 8 + 7] = fmaf(p, bh(u.w), o[c * 8 + 7]);
    }
  }

  float inv = 1.f / l;
  unsigned short* op = att + (size_t)(qy * 192 + qx) * DIMC + head * HDIM;
#pragma unroll
  for (int d = 0; d < 64; ++d) op[d] = f2bf(o[d] * inv);
}

// ---------- launch ----------
extern "C" void kernel_launch(void* const* d_in, const int* in_sizes, int n_in,
                              void* d_out, int out_size, void* d_ws, size_t ws_size,
                              hipStream_t stream) {
  const float* x      = (const float*)d_in[0];
  const float* n1g    = (const float*)d_in[1];
  const float* n1b    = (const float*)d_in[2];
  const float* qkv_w  = (const float*)d_in[3];
  const float* qkv_b  = (const float*)d_in[4];
  const float* rpb    = (const float*)d_in[5];
  const float* proj_w = (const float*)d_in[6];
  const float* proj_b = (const float*)d_in[7];
  const float* n2g    = (const float*)d_in[8];
  const float* n2b    = (const float*)d_in[9];
  const float* fc1_w  = (const float*)d_in[10];
  const float* fc1_b  = (const float*)d_in[11];
  const float* fc2_w  = (const float*)d_in[12];
  const float* fc2_b  = (const float*)d_in[13];
  float* out = (float*)d_out;

  char* ws = (char*)d_ws;
  // workspace layout (total ~137.2 MiB)
  unsigned short* xn   = (unsigned short*)ws;                           // L*384 bf16, reused as xn2
  unsigned short* qkvb = (unsigned short*)(ws + 28311552);              // L*1152 bf16, reused as h1
  unsigned short* att  = (unsigned short*)(ws + 28311552 + 84934656);   // L*384 bf16
  unsigned short* wq   = (unsigned short*)(ws + 141557760);             // 1152*384
  unsigned short* wp   = wq + 1152 * 384;                               // 384*384
  unsigned short* w1   = wp + 384 * 384;                                // 768*384
  unsigned short* w2   = w1 + 768 * 384;                                // 384*768

  // weight transposes (tiny)
  convt_kernel<<<(DIMC * 3 * DIMC + 255) / 256, 256, 0, stream>>>(qkv_w, wq, DIMC, 3 * DIMC);
  convt_kernel<<<(DIMC * DIMC + 255) / 256, 256, 0, stream>>>(proj_w, wp, DIMC, DIMC);
  convt_kernel<<<(DIMC * HIDD + 255) / 256, 256, 0, stream>>>(fc1_w, w1, DIMC, HIDD);
  convt_kernel<<<(HIDD * DIMC + 255) / 256, 256, 0, stream>>>(fc2_w, w2, HIDD, DIMC);

  // LN1
  ln_kernel<<<LTOK / 4, 256, 0, stream>>>(x, n1g, n1b, xn);
  // qkv = xn @ qkv_w + b   -> bf16 [L,1152]
  gemm_bf16<0><<<dim3(1152 / 128, LTOK / 128), 256, 0, stream>>>(xn, wq, qkv_b, nullptr, qkvb,
                                                                 LTOK, 1152, DIMC);
  // attention -> att bf16 [L,384]
  attn_kernel<<<dim3(NHEADS, 144), 256, 0, stream>>>(qkvb, rpb, att);
  // xa = x + att @ proj_w + b  -> fp32 in d_out
  gemm_bf16<1><<<dim3(DIMC / 128, LTOK / 128), 256, 0, stream>>>(att, wp, proj_b, x, out,
                                                                 LTOK, DIMC, DIMC);
  // LN2 (reads d_out)
  ln_kernel<<<LTOK / 4, 256, 0, stream>>>(out, n2g, n2b, xn);
  // h1 = gelu(xn2 @ fc1_w + b) -> bf16 [L,768] (reuse qkv buffer)
  gemm_bf16<2><<<dim3(HIDD / 128, LTOK / 128), 256, 0, stream>>>(xn, w1, fc1_b, nullptr, qkvb,
                                                                 LTOK, HIDD, DIMC);
  // out = xa + h1 @ fc2_w + b  (read-modify-write d_out, same-element per thread)
  gemm_bf16<1><<<dim3(DIMC / 128, LTOK / 128), 256, 0, stream>>>(qkvb, w2, fc2_b, out, out,
                                                                 LTOK, DIMC, HIDD);
}

// Round 2
// 412.221 us; speedup vs baseline: 4.0651x; 4.0651x over previous
//
#include <hip/hip_runtime.h>

// ---------- constants (problem is fixed-shape) ----------
#define LTOK 36864     // H*W = 192*192
#define DIMC 384
#define NHEADS 6
#define HDIM 64
#define HIDD 768
#define NWIN 12        // windows per side
#define WSZ 16
#define OWS 24
#define KVTOK 576      // 24*24
#define TBL 1521       // 39*39

using bf16x8 = __attribute__((ext_vector_type(8))) short;
using f32x4  = __attribute__((ext_vector_type(4))) float;
typedef unsigned short ushort_t;

__device__ inline float bl(unsigned u) { return __uint_as_float(u << 16); }
__device__ inline float bh(unsigned u) { return __uint_as_float(u & 0xFFFF0000u); }
__device__ inline unsigned short f2bf(float f) {
  unsigned u = __float_as_uint(f);
  return (unsigned short)((u + 0x7FFFu + ((u >> 16) & 1u)) >> 16);
}

// ---------- weight convert+transpose: wt[n*K+k] = bf16(w[k*N+n]) ----------
__global__ void convt_kernel(const float* __restrict__ w, unsigned short* __restrict__ wt,
                             int K, int N) {
  int id = blockIdx.x * 256 + threadIdx.x;
  if (id >= K * N) return;
  int n = id / K;
  int k = id - n * K;
  wt[id] = f2bf(w[(size_t)k * N + n]);
}

// ---------- rel-pos bias expand: biasm[head][q(256)][kt(576)] bf16 ----------
__global__ void rpb_expand_kernel(const float* __restrict__ rpb, unsigned short* __restrict__ biasm) {
  int id = blockIdx.x * 256 + threadIdx.x;
  if (id >= NHEADS * 256 * 576) return;
  int head = id / 147456;
  int rem = id - head * 147456;
  int q = rem / 576;
  int kt = rem - q * 576;
  int ty = q >> 4, tx = q & 15;
  int oy = kt / 24, ox = kt - (kt / 24) * 24;
  biasm[id] = f2bf(rpb[((ty - oy + 23) * 39 + (tx - ox + 23)) * NHEADS + head]);
}

// ---------- LayerNorm: fp32 in -> bf16 out, one wave per row (384 cols) ----------
__global__ __launch_bounds__(256) void ln_kernel(const float* __restrict__ x,
                                                 const float* __restrict__ g,
                                                 const float* __restrict__ b,
                                                 unsigned short* __restrict__ out) {
  int row = blockIdx.x * 4 + (threadIdx.x >> 6);
  int lane = threadIdx.x & 63;
  const float* xr = x + (size_t)row * DIMC;
  float v[6];
  float s = 0.f, ss = 0.f;
#pragma unroll
  for (int i = 0; i < 6; ++i) {
    v[i] = xr[lane + i * 64];
    s += v[i];
    ss += v[i] * v[i];
  }
#pragma unroll
  for (int off = 32; off; off >>= 1) {
    s += __shfl_xor(s, off);
    ss += __shfl_xor(ss, off);
  }
  float mean = s * (1.f / DIMC);
  float var = ss * (1.f / DIMC) - mean * mean;
  float rstd = rsqrtf(var + 1e-5f);
  unsigned short* outr = out + (size_t)row * DIMC;
#pragma unroll
  for (int i = 0; i < 6; ++i) {
    int c = lane + i * 64;
    outr[c] = f2bf((v[i] - mean) * rstd * g[c] + b[c]);
  }
}

// ---------- bf16 MFMA GEMM: C[M,N] = A[M,K] * Bt[N,K]^T + bias (+epilogue) ----------
template <int EPI>
__global__ __launch_bounds__(256) void gemm_bf16(const unsigned short* __restrict__ A,
                                                 const unsigned short* __restrict__ Bt,
                                                 const float* __restrict__ bias,
                                                 const float* __restrict__ resid,
                                                 void* __restrict__ outv,
                                                 int M, int N, int K) {
  __shared__ unsigned short As[128][40];
  __shared__ unsigned short Bs[128][40];
  const int tid = threadIdx.x;
  const int m0 = blockIdx.y * 128;
  const int n0 = blockIdx.x * 128;
  const int lane = tid & 63;
  const int wave = tid >> 6;
  const int wr = wave >> 1;
  const int wc = wave & 1;

  f32x4 acc[4][4];
#pragma unroll
  for (int i = 0; i < 4; ++i)
#pragma unroll
    for (int j = 0; j < 4; ++j) acc[i][j] = (f32x4){0.f, 0.f, 0.f, 0.f};

  const int lrow = tid >> 2;
  const int lcol = (tid & 3) * 8;

  for (int k0 = 0; k0 < K; k0 += 32) {
    __syncthreads();
    *(uint4*)&As[lrow][lcol]      = *(const uint4*)&A[(size_t)(m0 + lrow) * K + k0 + lcol];
    *(uint4*)&As[lrow + 64][lcol] = *(const uint4*)&A[(size_t)(m0 + lrow + 64) * K + k0 + lcol];
    *(uint4*)&Bs[lrow][lcol]      = *(const uint4*)&Bt[(size_t)(n0 + lrow) * K + k0 + lcol];
    *(uint4*)&Bs[lrow + 64][lcol] = *(const uint4*)&Bt[(size_t)(n0 + lrow + 64) * K + k0 + lcol];
    __syncthreads();

    const int kid = (lane >> 4) * 8;
    bf16x8 af[4], bfr[4];
#pragma unroll
    for (int i = 0; i < 4; ++i)
      af[i] = *(const bf16x8*)&As[wr * 64 + i * 16 + (lane & 15)][kid];
#pragma unroll
    for (int j = 0; j < 4; ++j)
      bfr[j] = *(const bf16x8*)&Bs[wc * 64 + j * 16 + (lane & 15)][kid];
#pragma unroll
    for (int i = 0; i < 4; ++i)
#pragma unroll
      for (int j = 0; j < 4; ++j)
        acc[i][j] = __builtin_amdgcn_mfma_f32_16x16x32_bf16(af[i], bfr[j], acc[i][j], 0, 0, 0);
  }

#pragma unroll
  for (int j = 0; j < 4; ++j) {
    int gcol = n0 + wc * 64 + j * 16 + (lane & 15);
    float bv = bias[gcol];
#pragma unroll
    for (int i = 0; i < 4; ++i) {
#pragma unroll
      for (int r = 0; r < 4; ++r) {
        int grow = m0 + wr * 64 + i * 16 + (lane >> 4) * 4 + r;
        float v = acc[i][j][r] + bv;
        size_t idx = (size_t)grow * N + gcol;
        if (EPI == 0) {
          ((unsigned short*)outv)[idx] = f2bf(v);
        } else if (EPI == 1) {
          ((float*)outv)[idx] = resid[idx] + v;
        } else {
          float gv = 0.5f * v * (1.f + erff(v * 0.70710678118654752f));
          ((unsigned short*)outv)[idx] = f2bf(gv);
        }
      }
    }
  }
}

// ---------- MFMA flash attention: one block per (head, window), 4 waves ----------
// wave w owns q rows [w*64, w*64+64); KV processed in 9 tiles of 64 tokens.
// Swapped QK^T: S^T tile via mfma(K, Q) -> per-lane q columns (lane&15).
__global__ __launch_bounds__(256, 2) void attn_kernel(const unsigned short* __restrict__ qkv,
                                                      const unsigned short* __restrict__ biasm,
                                                      unsigned short* __restrict__ att) {
  __shared__ unsigned short ks[2][64][72];   // K tile: [kt][d]
  __shared__ unsigned short vts[2][64][72];  // V^T tile: [d][kt]
  __shared__ unsigned short pt[4][64][72];   // per-wave P: [q][kt]
  const int head = blockIdx.x;
  const int win = blockIdx.y;
  const int wy = win / NWIN, wx = win - (win / NWIN) * NWIN;
  const int tid = threadIdx.x;
  const int w = tid >> 6, lane = tid & 63;
  const int l15 = lane & 15, l4 = lane >> 4;

  // ----- persistent Q fragments -----
  bf16x8 qf[4][2];
#pragma unroll
  for (int jq = 0; jq < 4; ++jq) {
    int q = w * 64 + jq * 16 + l15;
    int gy = wy * WSZ + (q >> 4), gx = wx * WSZ + (q & 15);
    const unsigned short* qp = qkv + (size_t)(gy * 192 + gx) * 1152 + head * HDIM + l4 * 8;
    qf[jq][0] = *(const bf16x8*)qp;
    qf[jq][1] = *(const bf16x8*)(qp + 32);
  }

  // ----- stage tile 0 (buffer 0): K rows + V^T scatter -----
  {
    int kt = lane;
    int oy = kt / OWS, ox = kt - (kt / OWS) * OWS;
    int gy = wy * WSZ + oy - 4, gx = wx * WSZ + ox - 4;
    uint4 k0 = {0,0,0,0}, k1 = {0,0,0,0}, v0 = {0,0,0,0}, v1 = {0,0,0,0};
    if ((unsigned)gy < 192u && (unsigned)gx < 192u) {
      const unsigned short* gp = qkv + (size_t)(gy * 192 + gx) * 1152 + DIMC + head * HDIM + w * 16;
      k0 = *(const uint4*)gp;        k1 = *(const uint4*)(gp + 8);
      v0 = *(const uint4*)(gp + 384); v1 = *(const uint4*)(gp + 392);
    }
    *(uint4*)&ks[0][lane][w * 16]     = k0;
    *(uint4*)&ks[0][lane][w * 16 + 8] = k1;
    const unsigned short* vv = (const unsigned short*)&v0;
#pragma unroll
    for (int j = 0; j < 8; ++j) vts[0][w * 16 + j][lane] = vv[j];
    vv = (const unsigned short*)&v1;
#pragma unroll
    for (int j = 0; j < 8; ++j) vts[0][w * 16 + 8 + j][lane] = vv[j];
  }
  __syncthreads();

  f32x4 oacc[4][4];
#pragma unroll
  for (int i = 0; i < 4; ++i)
#pragma unroll
    for (int j = 0; j < 4; ++j) oacc[i][j] = (f32x4){0.f, 0.f, 0.f, 0.f};
  float m[4] = {-1e30f, -1e30f, -1e30f, -1e30f};
  float lsum[4] = {0.f, 0.f, 0.f, 0.f};

  for (int kb = 0; kb < 9; ++kb) {
    const int cur = kb & 1;

    // ----- issue prefetch loads for tile kb+1 (written to LDS after PV) -----
    uint4 pk0 = {0,0,0,0}, pk1 = {0,0,0,0}, pv0 = {0,0,0,0}, pv1 = {0,0,0,0};
    const bool have = (kb + 1) < 9;
    if (have) {
      int kt = (kb + 1) * 64 + lane;
      int oy = kt / OWS, ox = kt - (kt / OWS) * OWS;
      int gy = wy * WSZ + oy - 4, gx = wx * WSZ + ox - 4;
      if ((unsigned)gy < 192u && (unsigned)gx < 192u) {
        const unsigned short* gp = qkv + (size_t)(gy * 192 + gx) * 1152 + DIMC + head * HDIM + w * 16;
        pk0 = *(const uint4*)gp;        pk1 = *(const uint4*)(gp + 8);
        pv0 = *(const uint4*)(gp + 384); pv1 = *(const uint4*)(gp + 392);
      }
    }

    // ----- S^T = K * Q^T : sacc[i(kt-tile)][j(q-tile)] -----
    f32x4 sacc[4][4];
#pragma unroll
    for (int i = 0; i < 4; ++i)
#pragma unroll
      for (int j = 0; j < 4; ++j) sacc[i][j] = (f32x4){0.f, 0.f, 0.f, 0.f};
    bf16x8 kf[4][2];
#pragma unroll
    for (int i = 0; i < 4; ++i) {
      kf[i][0] = *(const bf16x8*)&ks[cur][i * 16 + l15][l4 * 8];
      kf[i][1] = *(const bf16x8*)&ks[cur][i * 16 + l15][32 + l4 * 8];
    }
#pragma unroll
    for (int kk = 0; kk < 2; ++kk)
#pragma unroll
      for (int i = 0; i < 4; ++i)
#pragma unroll
        for (int j = 0; j < 4; ++j)
          sacc[i][j] = __builtin_amdgcn_mfma_f32_16x16x32_bf16(kf[i][kk], qf[j][kk], sacc[i][j], 0, 0, 0);

    // ----- bias (bf16, [head][q][kt]), s = acc*scale + bias -----
    uint2 bb[4][4];
    const int kbase = kb * 64;
#pragma unroll
    for (int i = 0; i < 4; ++i)
#pragma unroll
      for (int j = 0; j < 4; ++j) {
        int q = w * 64 + j * 16 + l15;
        bb[i][j] = *(const uint2*)&biasm[head * 147456 + q * 576 + kbase + i * 16 + l4 * 4];
      }

    float tmx[4] = {-1e30f, -1e30f, -1e30f, -1e30f};
#pragma unroll
    for (int i = 0; i < 4; ++i)
#pragma unroll
      for (int j = 0; j < 4; ++j) {
        sacc[i][j][0] = fmaf(sacc[i][j][0], 0.125f, bl(bb[i][j].x));
        sacc[i][j][1] = fmaf(sacc[i][j][1], 0.125f, bh(bb[i][j].x));
        sacc[i][j][2] = fmaf(sacc[i][j][2], 0.125f, bl(bb[i][j].y));
        sacc[i][j][3] = fmaf(sacc[i][j][3], 0.125f, bh(bb[i][j].y));
        tmx[j] = fmaxf(tmx[j], fmaxf(fmaxf(sacc[i][j][0], sacc[i][j][1]),
                                     fmaxf(sacc[i][j][2], sacc[i][j][3])));
      }
#pragma unroll
    for (int j = 0; j < 4; ++j) {
      tmx[j] = fmaxf(tmx[j], __shfl_xor(tmx[j], 16));
      tmx[j] = fmaxf(tmx[j], __shfl_xor(tmx[j], 32));
    }

    // defer-max guard (T13): rescale only when max grew past threshold
    bool skip = __all(tmx[0] <= m[0] + 8.f && tmx[1] <= m[1] + 8.f &&
                      tmx[2] <= m[2] + 8.f && tmx[3] <= m[3] + 8.f);
    if (!skip) {
      float sc[4];
#pragma unroll
      for (int j = 0; j < 4; ++j) {
        float nm = fmaxf(m[j], tmx[j]);
        sc[j] = __expf(m[j] - nm);
        m[j] = nm;
        lsum[j] *= sc[j];
      }
#pragma unroll
      for (int i = 0; i < 4; ++i)
#pragma unroll
        for (int r = 0; r < 4; ++r) {
          float rs = __shfl(sc[i], l4 * 4 + r);
#pragma unroll
          for (int jd = 0; jd < 4; ++jd) oacc[i][jd][r] *= rs;
        }
    }

    // ----- P = exp(s - m), row sums, pack to LDS -----
    float rsum[4] = {0.f, 0.f, 0.f, 0.f};
#pragma unroll
    for (int i = 0; i < 4; ++i)
#pragma unroll
      for (int j = 0; j < 4; ++j) {
#pragma unroll
        for (int r = 0; r < 4; ++r) {
          float p = __expf(sacc[i][j][r] - m[j]);
          sacc[i][j][r] = p;
          rsum[j] += p;
        }
      }
#pragma unroll
    for (int j = 0; j < 4; ++j) {
      rsum[j] += __shfl_xor(rsum[j], 16);
      rsum[j] += __shfl_xor(rsum[j], 32);
      lsum[j] += rsum[j];
    }
#pragma unroll
    for (int i = 0; i < 4; ++i)
#pragma unroll
      for (int j = 0; j < 4; ++j) {
        ushort4 pk;
        pk.x = f2bf(sacc[i][j][0]);
        pk.y = f2bf(sacc[i][j][1]);
        pk.z = f2bf(sacc[i][j][2]);
        pk.w = f2bf(sacc[i][j][3]);
        *(ushort4*)&pt[w][j * 16 + l15][i * 16 + l4 * 4] = pk;
      }

    // ----- O += P * V : A = pt[q][kt], B = vts[d][kt] -----
    bf16x8 pf[4][2], vf[4][2];
#pragma unroll
    for (int iq = 0; iq < 4; ++iq) {
      pf[iq][0] = *(const bf16x8*)&pt[w][iq * 16 + l15][l4 * 8];
      pf[iq][1] = *(const bf16x8*)&pt[w][iq * 16 + l15][32 + l4 * 8];
    }
#pragma unroll
    for (int jd = 0; jd < 4; ++jd) {
      vf[jd][0] = *(const bf16x8*)&vts[cur][jd * 16 + l15][l4 * 8];
      vf[jd][1] = *(const bf16x8*)&vts[cur][jd * 16 + l15][32 + l4 * 8];
    }
#pragma unroll
    for (int kk = 0; kk < 2; ++kk)
#pragma unroll
      for (int iq = 0; iq < 4; ++iq)
#pragma unroll
        for (int jd = 0; jd < 4; ++jd)
          oacc[iq][jd] = __builtin_amdgcn_mfma_f32_16x16x32_bf16(pf[iq][kk], vf[jd][kk], oacc[iq][jd], 0, 0, 0);

    // ----- write staged tile kb+1 -----
    if (have) {
      *(uint4*)&ks[cur ^ 1][lane][w * 16]     = pk0;
      *(uint4*)&ks[cur ^ 1][lane][w * 16 + 8] = pk1;
      const unsigned short* vv = (const unsigned short*)&pv0;
#pragma unroll
      for (int j = 0; j < 8; ++j) vts[cur ^ 1][w * 16 + j][lane] = vv[j];
      vv = (const unsigned short*)&pv1;
#pragma unroll
      for (int j = 0; j < 8; ++j) vts[cur ^ 1][w * 16 + 8 + j][lane] = vv[j];
    }
    __syncthreads();
  }

  // ----- epilogue: normalize + store -----
  float invl[4];
#pragma unroll
  for (int j = 0; j < 4; ++j) invl[j] = 1.f / lsum[j];
#pragma unroll
  for (int i = 0; i < 4; ++i) {
#pragma unroll
    for (int r = 0; r < 4; ++r) {
      float il = __shfl(invl[i], l4 * 4 + r);
      int q = w * 64 + i * 16 + l4 * 4 + r;
      int gy = wy * WSZ + (q >> 4), gx = wx * WSZ + (q & 15);
      unsigned short* op = att + (size_t)(gy * 192 + gx) * DIMC + head * HDIM + l15;
#pragma unroll
      for (int jd = 0; jd < 4; ++jd) op[jd * 16] = f2bf(oacc[i][jd][r] * il);
    }
  }
}

// ---------- launch ----------
extern "C" void kernel_launch(void* const* d_in, const int* in_sizes, int n_in,
                              void* d_out, int out_size, void* d_ws, size_t ws_size,
                              hipStream_t stream) {
  const float* x      = (const float*)d_in[0];
  const float* n1g    = (const float*)d_in[1];
  const float* n1b    = (const float*)d_in[2];
  const float* qkv_w  = (const float*)d_in[3];
  const float* qkv_b  = (const float*)d_in[4];
  const float* rpb    = (const float*)d_in[5];
  const float* proj_w = (const float*)d_in[6];
  const float* proj_b = (const float*)d_in[7];
  const float* n2g    = (const float*)d_in[8];
  const float* n2b    = (const float*)d_in[9];
  const float* fc1_w  = (const float*)d_in[10];
  const float* fc1_b  = (const float*)d_in[11];
  const float* fc2_w  = (const float*)d_in[12];
  const float* fc2_b  = (const float*)d_in[13];
  float* out = (float*)d_out;

  char* ws = (char*)d_ws;
  unsigned short* xn   = (unsigned short*)ws;                           // L*384 bf16 (LN out); head also reused for biasm during attn
  unsigned short* qkvb = (unsigned short*)(ws + 28311552);              // L*1152 bf16, reused as h1
  unsigned short* att  = (unsigned short*)(ws + 28311552 + 84934656);   // L*384 bf16
  unsigned short* wq   = (unsigned short*)(ws + 141557760);             // 1152*384
  unsigned short* wp   = wq + 1152 * 384;                               // 384*384
  unsigned short* w1   = wp + 384 * 384;                                // 768*384
  unsigned short* w2   = w1 + 768 * 384;                                // 384*768
  unsigned short* biasm = xn;  // 884736 bf16; valid between qkv GEMM and LN2

  convt_kernel<<<(DIMC * 3 * DIMC + 255) / 256, 256, 0, stream>>>(qkv_w, wq, DIMC, 3 * DIMC);
  convt_kernel<<<(DIMC * DIMC + 255) / 256, 256, 0, stream>>>(proj_w, wp, DIMC, DIMC);
  convt_kernel<<<(DIMC * HIDD + 255) / 256, 256, 0, stream>>>(fc1_w, w1, DIMC, HIDD);
  convt_kernel<<<(HIDD * DIMC + 255) / 256, 256, 0, stream>>>(fc2_w, w2, HIDD, DIMC);

  // LN1
  ln_kernel<<<LTOK / 4, 256, 0, stream>>>(x, n1g, n1b, xn);
  // qkv = xn @ qkv_w + b
  gemm_bf16<0><<<dim3(1152 / 128, LTOK / 128), 256, 0, stream>>>(xn, wq, qkv_b, nullptr, qkvb,
                                                                 LTOK, 1152, DIMC);
  // bias matrix expand (into xn region — xn no longer needed until LN2 rewrites it)
  rpb_expand_kernel<<<(NHEADS * 256 * 576 + 255) / 256, 256, 0, stream>>>(rpb, biasm);
  // attention
  attn_kernel<<<dim3(NHEADS, 144), 256, 0, stream>>>(qkvb, biasm, att);
  // xa = x + att @ proj_w + b
  gemm_bf16<1><<<dim3(DIMC / 128, LTOK / 128), 256, 0, stream>>>(att, wp, proj_b, x, out,
                                                                 LTOK, DIMC, DIMC);
  // LN2
  ln_kernel<<<LTOK / 4, 256, 0, stream>>>(out, n2g, n2b, xn);
  // h1 = gelu(xn @ fc1_w + b)
  gemm_bf16<2><<<dim3(HIDD / 128, LTOK / 128), 256, 0, stream>>>(xn, w1, fc1_b, nullptr, qkvb,
                                                                 LTOK, HIDD, DIMC);
  // out = xa + h1 @ fc2_w + b
  gemm_bf16<1><<<dim3(DIMC / 128, LTOK / 128), 256, 0, stream>>>(qkvb, w2, fc2_b, out, out,
                                                                 LTOK, DIMC, HIDD);
}